// Round 1
// baseline (750.976 us; speedup 1.0000x reference)
//
#include <hip/hip_runtime.h>
#include <cstdint>
#include <cstddef>

#define B_    4096
#define LAT   64
#define FRAME 512
#define HID   1024
#define NE    8
#define GH    128
#define IN1   576   // LAT + FRAME
#define IN2   1088  // LAT + HID

typedef __bf16 bf16x8 __attribute__((ext_vector_type(8)));
typedef float  f32x4  __attribute__((ext_vector_type(4)));

// round-to-nearest-even fp32 -> bf16 (values are finite; no NaN path needed)
__device__ inline unsigned short f2bf(float f) {
  union { float f; uint32_t u; } c; c.f = f;
  uint32_t u = c.u;
  return (unsigned short)((u + 0x7FFFu + ((u >> 16) & 1u)) >> 16);
}

// async global->LDS, 16B per lane; LDS dest = wave-uniform base + lane*16
__device__ inline void async16(const void* g, void* l) {
  __builtin_amdgcn_global_load_lds(
      (__attribute__((address_space(1))) void*)(void*)g,
      (__attribute__((address_space(3))) void*)l, 16, 0, 0);
}

// ---------------- gate MLP -> coef [B, 8] fp32 ----------------
__global__ __launch_bounds__(256) void gate_kernel(
    const float* __restrict__ z, const float* __restrict__ c,
    const float* __restrict__ gw1, const float* __restrict__ gb1,
    const float* __restrict__ gw2, const float* __restrict__ gb2,
    const float* __restrict__ gw3, const float* __restrict__ gb3,
    float* __restrict__ coef)
{
  __shared__ float xs[16][IN1 + 1];
  __shared__ float hs[16][GH + 1];
  __shared__ float h2s[16][GH + 1];
  __shared__ float ls[16][NE];
  const int tid = threadIdx.x;
  const int r0 = blockIdx.x * 16;

  for (int i = tid; i < 16 * IN1; i += 256) {
    int r = i / IN1, j = i - r * IN1;
    xs[r][j] = (j < LAT) ? z[(size_t)(r0 + r) * LAT + j]
                         : c[(size_t)(r0 + r) * FRAME + (j - LAT)];
  }
  __syncthreads();
  {
    const int col = tid & 127, rbase = tid >> 7;
    float acc[8];
    for (int q = 0; q < 8; ++q) acc[q] = gb1[col];
    for (int i = 0; i < IN1; ++i) {
      float w = gw1[(size_t)i * GH + col];
      for (int q = 0; q < 8; ++q) acc[q] += w * xs[rbase + 2 * q][i];
    }
    for (int q = 0; q < 8; ++q) {
      float v = acc[q];
      hs[rbase + 2 * q][col] = v > 0.f ? v : expm1f(v);
    }
  }
  __syncthreads();
  {
    const int col = tid & 127, rbase = tid >> 7;
    float acc[8];
    for (int q = 0; q < 8; ++q) acc[q] = gb2[col];
    for (int i = 0; i < GH; ++i) {
      float w = gw2[(size_t)i * GH + col];
      for (int q = 0; q < 8; ++q) acc[q] += w * hs[rbase + 2 * q][i];
    }
    for (int q = 0; q < 8; ++q) {
      float v = acc[q];
      h2s[rbase + 2 * q][col] = v > 0.f ? v : expm1f(v);
    }
  }
  __syncthreads();
  if (tid < 128) {
    int r = tid >> 3, e = tid & 7;
    float acc = gb3[e];
    for (int i = 0; i < GH; ++i) acc += h2s[r][i] * gw3[(size_t)i * NE + e];
    ls[r][e] = acc;
  }
  __syncthreads();
  if (tid < 16) {
    int r = tid;
    float m = ls[r][0];
    for (int e = 1; e < NE; ++e) m = fmaxf(m, ls[r][e]);
    float ex[NE], s = 0.f;
    for (int e = 0; e < NE; ++e) { ex[e] = expf(ls[r][e] - m); s += ex[e]; }
    float inv = 1.f / s;
    for (int e = 0; e < NE; ++e) coef[(size_t)(r0 + r) * NE + e] = ex[e] * inv;
  }
}

// -------- build bf16 x1 = [z|c], and z-columns of x2/x3 --------
__global__ __launch_bounds__(256) void build_x(
    const float* __restrict__ z, const float* __restrict__ c,
    unsigned short* __restrict__ x1, unsigned short* __restrict__ x2,
    unsigned short* __restrict__ x3)
{
  int idx = blockIdx.x * 256 + threadIdx.x;
  if (idx >= B_ * IN1) return;
  int b = idx / IN1, j = idx - b * IN1;
  float v = (j < LAT) ? z[(size_t)b * LAT + j] : c[(size_t)b * FRAME + (j - LAT)];
  unsigned short h = f2bf(v);
  x1[(size_t)b * IN1 + j] = h;
  if (j < LAT) {
    x2[(size_t)b * IN2 + j] = h;
    x3[(size_t)b * IN2 + j] = h;
  }
}

// -------- weights [E,K,N] fp32 -> [E,N,K] bf16 (transpose+cast) --------
__global__ __launch_bounds__(256) void transpose_cast(
    const float* __restrict__ in, unsigned short* __restrict__ out, int K, int N)
{
  __shared__ float t[32][33];
  const int e = blockIdx.z;
  const int n0 = blockIdx.x * 32, k0 = blockIdx.y * 32;
  const float* ine = in + (size_t)e * K * N;
  unsigned short* oute = out + (size_t)e * N * K;
  const int tx = threadIdx.x, ty = threadIdx.y;
  for (int it = 0; it < 4; ++it)
    t[ty + it * 8][tx] = ine[(size_t)(k0 + ty + it * 8) * N + n0 + tx];
  __syncthreads();
  for (int it = 0; it < 4; ++it)
    oute[(size_t)(n0 + ty + it * 8) * K + k0 + tx] = f2bf(t[tx][ty + it * 8]);
}

// -------- MoE GEMM: out[b,n] = sum_e coef[b,e]*(x[b,:] @ w[e,:,n] + bias[e,n]) --------
// X [B,KDIM] bf16 row-major; Wt [E,NOUT,KDIM] bf16 (N-major = B^T layout);
// e-outer loop, per-expert fp32 accumulator folded with fp32 coef.
template<int KDIM, int NOUT, bool ELU_ACT, bool FINAL>
__global__ __launch_bounds__(256) void gemm_moe(
    const unsigned short* __restrict__ X,
    const unsigned short* __restrict__ Wt,
    const float* __restrict__ bias,
    const float* __restrict__ coef,
    unsigned short* __restrict__ next_x,
    float* __restrict__ outf)
{
  __shared__ __align__(16) unsigned short As[128 * 64];
  __shared__ __align__(16) unsigned short Bs[128 * 64];
  __shared__ float coefS[128 * NE];
  __shared__ float biasS[NE * 128];

  const int tid = threadIdx.x;
  const int wave = tid >> 6, lane = tid & 63;
  const int wm = wave & 1, wn = wave >> 1;     // 2x2 waves, each 64x64
  const int quad = lane >> 4, l16 = lane & 15;
  const int bm0 = blockIdx.x * 128, bn0 = blockIdx.y * 128;

  for (int i = tid; i < 128 * NE; i += 256)
    coefS[i] = coef[(size_t)(bm0 + (i >> 3)) * NE + (i & 7)];
  for (int i = tid; i < NE * 128; i += 256)
    biasS[i] = bias[(size_t)(i >> 7) * NOUT + bn0 + (i & 127)];

  f32x4 accT[4][4];
  #pragma unroll
  for (int mi = 0; mi < 4; ++mi)
    #pragma unroll
    for (int ni = 0; ni < 4; ++ni)
      #pragma unroll
      for (int r = 0; r < 4; ++r) accT[mi][ni][r] = 0.f;

  const int rstage = wave * 8 + (lane >> 3);  // + it*32 -> tile row
  const int kstage = (lane & 7) * 8;          // k sub-offset (8 bf16 = 16B)
  const int ldsoff = wave * 512;              // elements; + it*2048

  for (int e = 0; e < NE; ++e) {
    const size_t eoff = (size_t)e * NOUT * KDIM;
    f32x4 accE[4][4];
    #pragma unroll
    for (int mi = 0; mi < 4; ++mi)
      #pragma unroll
      for (int ni = 0; ni < 4; ++ni)
        #pragma unroll
        for (int r = 0; r < 4; ++r) accE[mi][ni][r] = 0.f;

    for (int k0 = 0; k0 < KDIM; k0 += 64) {
      #pragma unroll
      for (int it = 0; it < 4; ++it) {
        const int row = it * 32 + rstage;
        async16(X + (size_t)(bm0 + row) * KDIM + k0 + kstage, &As[it * 2048 + ldsoff]);
        async16(Wt + eoff + (size_t)(bn0 + row) * KDIM + k0 + kstage, &Bs[it * 2048 + ldsoff]);
      }
      __syncthreads();   // drains vmcnt (global_load_lds) per m97 semantics
      #pragma unroll
      for (int ks = 0; ks < 64; ks += 32) {
        bf16x8 af[4], bfv[4];
        #pragma unroll
        for (int mi = 0; mi < 4; ++mi)
          af[mi] = *(const bf16x8*)&As[(wm * 64 + mi * 16 + l16) * 64 + ks + quad * 8];
        #pragma unroll
        for (int ni = 0; ni < 4; ++ni)
          bfv[ni] = *(const bf16x8*)&Bs[(wn * 64 + ni * 16 + l16) * 64 + ks + quad * 8];
        #pragma unroll
        for (int mi = 0; mi < 4; ++mi)
          #pragma unroll
          for (int ni = 0; ni < 4; ++ni)
            accE[mi][ni] = __builtin_amdgcn_mfma_f32_16x16x32_bf16(
                af[mi], bfv[ni], accE[mi][ni], 0, 0, 0);
      }
      __syncthreads();
    }
    // fold expert e with fp32 coef (C/D layout: row = quad*4+r, col = l16)
    #pragma unroll
    for (int mi = 0; mi < 4; ++mi) {
      float cf[4];
      #pragma unroll
      for (int r = 0; r < 4; ++r)
        cf[r] = coefS[(wm * 64 + mi * 16 + quad * 4 + r) * NE + e];
      #pragma unroll
      for (int ni = 0; ni < 4; ++ni)
        #pragma unroll
        for (int r = 0; r < 4; ++r)
          accT[mi][ni][r] += cf[r] * accE[mi][ni][r];
    }
  }

  // epilogue: + coef@bias, ELU, write bf16 into next layer's input (or fp32 final)
  #pragma unroll
  for (int mi = 0; mi < 4; ++mi) {
    #pragma unroll
    for (int r = 0; r < 4; ++r) {
      const int m_loc = wm * 64 + mi * 16 + quad * 4 + r;
      const size_t grow = (size_t)(bm0 + m_loc);
      #pragma unroll
      for (int ni = 0; ni < 4; ++ni) {
        const int n_loc = wn * 64 + ni * 16 + l16;
        float v = accT[mi][ni][r];
        #pragma unroll
        for (int e = 0; e < NE; ++e)
          v += coefS[m_loc * NE + e] * biasS[e * 128 + n_loc];
        if (ELU_ACT) v = v > 0.f ? v : expm1f(v);
        if (FINAL) outf[grow * NOUT + bn0 + n_loc] = v;
        else       next_x[grow * IN2 + LAT + bn0 + n_loc] = f2bf(v);
      }
    }
  }
}

extern "C" void kernel_launch(void* const* d_in, const int* in_sizes, int n_in,
                              void* d_out, int out_size, void* d_ws, size_t ws_size,
                              hipStream_t stream)
{
  const float* z   = (const float*)d_in[0];
  const float* c   = (const float*)d_in[1];
  const float* w0  = (const float*)d_in[2];
  const float* b0  = (const float*)d_in[3];
  const float* w1  = (const float*)d_in[4];
  const float* b1  = (const float*)d_in[5];
  const float* w2  = (const float*)d_in[6];
  const float* b2  = (const float*)d_in[7];
  const float* gw1 = (const float*)d_in[8];
  const float* gb1 = (const float*)d_in[9];
  const float* gw2 = (const float*)d_in[10];
  const float* gb2 = (const float*)d_in[11];
  const float* gw3 = (const float*)d_in[12];
  const float* gb3 = (const float*)d_in[13];
  float* out = (float*)d_out;

  // workspace layout (bytes), total ~58.9 MB
  char* ws = (char*)d_ws;
  float*          coef = (float*)         (ws + 0);          // 4096*8*4    = 131072
  unsigned short* x1   = (unsigned short*)(ws + 131072);     // 4096*576*2  = 4718592
  unsigned short* x2   = (unsigned short*)(ws + 4849664);    // 4096*1088*2 = 8912896
  unsigned short* x3   = (unsigned short*)(ws + 13762560);   // 8912896
  unsigned short* Wt0  = (unsigned short*)(ws + 22675456);   // 8*1024*576*2  = 9437184
  unsigned short* Wt1  = (unsigned short*)(ws + 32112640);   // 8*1024*1088*2 = 17825792
  unsigned short* Wt2  = (unsigned short*)(ws + 49938432);   // 8*512*1088*2  = 8912896

  gate_kernel<<<B_ / 16, 256, 0, stream>>>(z, c, gw1, gb1, gw2, gb2, gw3, gb3, coef);
  build_x<<<(B_ * IN1) / 256, 256, 0, stream>>>(z, c, x1, x2, x3);
  transpose_cast<<<dim3(HID / 32, IN1 / 32, NE), dim3(32, 8), 0, stream>>>(w0, Wt0, IN1, HID);
  transpose_cast<<<dim3(HID / 32, IN2 / 32, NE), dim3(32, 8), 0, stream>>>(w1, Wt1, IN2, HID);
  transpose_cast<<<dim3(FRAME / 32, IN2 / 32, NE), dim3(32, 8), 0, stream>>>(w2, Wt2, IN2, FRAME);

  gemm_moe<IN1, HID, true, false><<<dim3(32, 8), 256, 0, stream>>>(x1, Wt0, b0, coef, x2, nullptr);
  gemm_moe<IN2, HID, true, false><<<dim3(32, 8), 256, 0, stream>>>(x2, Wt1, b1, coef, x3, nullptr);
  gemm_moe<IN2, FRAME, false, true><<<dim3(32, 4), 256, 0, stream>>>(x3, Wt2, b2, coef, nullptr, out);
}

// Round 2
// 676.634 us; speedup vs baseline: 1.1099x; 1.1099x over previous
//
#include <hip/hip_runtime.h>
#include <cstdint>
#include <cstddef>

#define B_    4096
#define LAT   64
#define FRAME 512
#define HID   1024
#define NE    8
#define GH    128
#define IN1   576   // LAT + FRAME
#define IN2   1088  // LAT + HID

typedef __bf16 bf16x8 __attribute__((ext_vector_type(8)));
typedef float  f32x4  __attribute__((ext_vector_type(4)));

// round-to-nearest-even fp32 -> bf16
__device__ inline unsigned short f2bf(float f) {
  union { float f; uint32_t u; } c; c.f = f;
  uint32_t u = c.u;
  return (unsigned short)((u + 0x7FFFu + ((u >> 16) & 1u)) >> 16);
}

// async global->LDS, 16B per lane; LDS dest = wave-uniform base + lane*16
__device__ inline void async16(const void* g, void* l) {
  __builtin_amdgcn_global_load_lds(
      (__attribute__((address_space(1))) void*)(void*)g,
      (__attribute__((address_space(3))) void*)l, 16, 0, 0);
}

// ---------------- gate MLP -> coef [B, 8] fp32 ----------------
__global__ __launch_bounds__(256) void gate_kernel(
    const float* __restrict__ z, const float* __restrict__ c,
    const float* __restrict__ gw1, const float* __restrict__ gb1,
    const float* __restrict__ gw2, const float* __restrict__ gb2,
    const float* __restrict__ gw3, const float* __restrict__ gb3,
    float* __restrict__ coef)
{
  __shared__ float xs[16][IN1 + 1];
  __shared__ float hs[16][GH + 1];
  __shared__ float h2s[16][GH + 1];
  __shared__ float ls[16][NE];
  const int tid = threadIdx.x;
  const int r0 = blockIdx.x * 16;

  for (int i = tid; i < 16 * IN1; i += 256) {
    int r = i / IN1, j = i - r * IN1;
    xs[r][j] = (j < LAT) ? z[(size_t)(r0 + r) * LAT + j]
                         : c[(size_t)(r0 + r) * FRAME + (j - LAT)];
  }
  __syncthreads();
  {
    const int col = tid & 127, rbase = tid >> 7;
    float acc[8];
    for (int q = 0; q < 8; ++q) acc[q] = gb1[col];
    for (int i = 0; i < IN1; ++i) {
      float w = gw1[(size_t)i * GH + col];
      for (int q = 0; q < 8; ++q) acc[q] += w * xs[rbase + 2 * q][i];
    }
    for (int q = 0; q < 8; ++q) {
      float v = acc[q];
      hs[rbase + 2 * q][col] = v > 0.f ? v : expm1f(v);
    }
  }
  __syncthreads();
  {
    const int col = tid & 127, rbase = tid >> 7;
    float acc[8];
    for (int q = 0; q < 8; ++q) acc[q] = gb2[col];
    for (int i = 0; i < GH; ++i) {
      float w = gw2[(size_t)i * GH + col];
      for (int q = 0; q < 8; ++q) acc[q] += w * hs[rbase + 2 * q][i];
    }
    for (int q = 0; q < 8; ++q) {
      float v = acc[q];
      h2s[rbase + 2 * q][col] = v > 0.f ? v : expm1f(v);
    }
  }
  __syncthreads();
  if (tid < 128) {
    int r = tid >> 3, e = tid & 7;
    float acc = gb3[e];
    for (int i = 0; i < GH; ++i) acc += h2s[r][i] * gw3[(size_t)i * NE + e];
    ls[r][e] = acc;
  }
  __syncthreads();
  if (tid < 16) {
    int r = tid;
    float m = ls[r][0];
    for (int e = 1; e < NE; ++e) m = fmaxf(m, ls[r][e]);
    float ex[NE], s = 0.f;
    for (int e = 0; e < NE; ++e) { ex[e] = expf(ls[r][e] - m); s += ex[e]; }
    float inv = 1.f / s;
    for (int e = 0; e < NE; ++e) coef[(size_t)(r0 + r) * NE + e] = ex[e] * inv;
  }
}

// -------- build bf16 x1 = [z|c], and z-columns of x2/x3 --------
__global__ __launch_bounds__(256) void build_x(
    const float* __restrict__ z, const float* __restrict__ c,
    unsigned short* __restrict__ x1, unsigned short* __restrict__ x2,
    unsigned short* __restrict__ x3)
{
  int idx = blockIdx.x * 256 + threadIdx.x;
  if (idx >= B_ * IN1) return;
  int b = idx / IN1, j = idx - b * IN1;
  float v = (j < LAT) ? z[(size_t)b * LAT + j] : c[(size_t)b * FRAME + (j - LAT)];
  unsigned short h = f2bf(v);
  x1[(size_t)b * IN1 + j] = h;
  if (j < LAT) {
    x2[(size_t)b * IN2 + j] = h;
    x3[(size_t)b * IN2 + j] = h;
  }
}

// -------- weights [E,K,N] fp32 -> [E,N,K] bf16 (transpose+cast) --------
__global__ __launch_bounds__(256) void transpose_cast(
    const float* __restrict__ in, unsigned short* __restrict__ out, int K, int N)
{
  __shared__ float t[32][33];
  const int e = blockIdx.z;
  const int n0 = blockIdx.x * 32, k0 = blockIdx.y * 32;
  const float* ine = in + (size_t)e * K * N;
  unsigned short* oute = out + (size_t)e * N * K;
  const int tx = threadIdx.x, ty = threadIdx.y;
  for (int it = 0; it < 4; ++it)
    t[ty + it * 8][tx] = ine[(size_t)(k0 + ty + it * 8) * N + n0 + tx];
  __syncthreads();
  for (int it = 0; it < 4; ++it)
    oute[(size_t)(n0 + ty + it * 8) * K + k0 + tx] = f2bf(t[tx][ty + it * 8]);
}

// -------- MoE GEMM: out[b,n] = sum_e coef[b,e]*(x[b,:] @ w[e,:,n] + bias[e,n]) --------
// Tile 128x64, 4 waves (2x2, each 64x32). e-outer loop with per-expert accE
// folded into accT (acc total = 64 VGPRs -> no spill). LDS k-granules
// XOR-swizzled by (row&7) to kill the 16-way quad bank conflict.
// FINAL: split over experts via gridDim.z (ECNT experts each), fp32 atomicAdd.
template<int KDIM, int NOUT, int ECNT, bool ELU_ACT, bool FINAL>
__global__ __launch_bounds__(256) void gemm_moe(
    const unsigned short* __restrict__ X,
    const unsigned short* __restrict__ Wt,   // [8][NOUT][KDIM]
    const float* __restrict__ bias,          // [8][NOUT]
    const float* __restrict__ coef,          // [B][8]
    unsigned short* __restrict__ next_x,     // [B][IN2] (cols 64..)
    float* __restrict__ outf)                // [B][NOUT] (FINAL, zero-init)
{
  __shared__ __align__(16) unsigned short As[128 * 64];
  __shared__ __align__(16) unsigned short Bs[64 * 64];
  __shared__ float coefS[128 * NE];
  __shared__ float biasS[NE * 64];

  const int tid = threadIdx.x;
  const int wave = tid >> 6, lane = tid & 63;
  const int wm = wave & 1, wn = wave >> 1;
  const int quad = lane >> 4, l16 = lane & 15;
  const int bm0 = blockIdx.x * 128, bn0 = blockIdx.y * 64;
  const int ebase = FINAL ? blockIdx.z * ECNT : 0;

  for (int i = tid; i < 128 * NE; i += 256)
    coefS[i] = coef[(size_t)(bm0 + (i >> 3)) * NE + (i & 7)];
  for (int i = tid; i < NE * 64; i += 256)
    biasS[i] = bias[(size_t)(i >> 6) * NOUT + bn0 + (i & 63)];

  f32x4 accT[4][2];
  #pragma unroll
  for (int mi = 0; mi < 4; ++mi)
    #pragma unroll
    for (int ni = 0; ni < 2; ++ni)
      #pragma unroll
      for (int r = 0; r < 4; ++r) accT[mi][ni][r] = 0.f;

  // staging: lane covers 16B granule; source k-granule swizzled by row&7
  const int srow  = wave * 8 + (lane >> 3);                    // + it*32
  const int skoff = (((lane & 7) ^ ((lane >> 3) & 7)) * 8);    // elems

  for (int e = 0; e < ECNT; ++e) {
    const size_t eoff = (size_t)(ebase + e) * NOUT * KDIM;
    f32x4 accE[4][2];
    #pragma unroll
    for (int mi = 0; mi < 4; ++mi)
      #pragma unroll
      for (int ni = 0; ni < 2; ++ni)
        #pragma unroll
        for (int r = 0; r < 4; ++r) accE[mi][ni][r] = 0.f;

    for (int k0 = 0; k0 < KDIM; k0 += 64) {
      #pragma unroll
      for (int it = 0; it < 4; ++it)
        async16(X + (size_t)(bm0 + it * 32 + srow) * KDIM + k0 + skoff,
                &As[it * 2048 + wave * 512]);
      #pragma unroll
      for (int it = 0; it < 2; ++it)
        async16(Wt + eoff + (size_t)(bn0 + it * 32 + srow) * KDIM + k0 + skoff,
                &Bs[it * 2048 + wave * 512]);
      __syncthreads();
      #pragma unroll
      for (int ks = 0; ks < 64; ks += 32) {
        bf16x8 af[4], bv[2];
        #pragma unroll
        for (int mi = 0; mi < 4; ++mi) {
          const int r = wm * 64 + mi * 16 + l16;
          const int g = (ks / 8 + quad) ^ (r & 7);
          af[mi] = *(const bf16x8*)&As[r * 64 + g * 8];
        }
        #pragma unroll
        for (int ni = 0; ni < 2; ++ni) {
          const int r = wn * 32 + ni * 16 + l16;
          const int g = (ks / 8 + quad) ^ (r & 7);
          bv[ni] = *(const bf16x8*)&Bs[r * 64 + g * 8];
        }
        #pragma unroll
        for (int mi = 0; mi < 4; ++mi)
          #pragma unroll
          for (int ni = 0; ni < 2; ++ni)
            accE[mi][ni] = __builtin_amdgcn_mfma_f32_16x16x32_bf16(
                af[mi], bv[ni], accE[mi][ni], 0, 0, 0);
      }
      __syncthreads();
    }
    // fold expert (C/D layout: row = quad*4+r, col = l16)
    #pragma unroll
    for (int mi = 0; mi < 4; ++mi) {
      float cf[4];
      #pragma unroll
      for (int r = 0; r < 4; ++r)
        cf[r] = coefS[(wm * 64 + mi * 16 + quad * 4 + r) * NE + ebase + e];
      #pragma unroll
      for (int ni = 0; ni < 2; ++ni)
        #pragma unroll
        for (int r = 0; r < 4; ++r)
          accT[mi][ni][r] += cf[r] * accE[mi][ni][r];
    }
  }

  // epilogue
  #pragma unroll
  for (int mi = 0; mi < 4; ++mi) {
    #pragma unroll
    for (int r = 0; r < 4; ++r) {
      const int m_loc = wm * 64 + mi * 16 + quad * 4 + r;
      const size_t grow = (size_t)(bm0 + m_loc);
      #pragma unroll
      for (int ni = 0; ni < 2; ++ni) {
        const int n_loc = wn * 32 + ni * 16 + l16;
        float v = accT[mi][ni][r];
        if (!FINAL || blockIdx.z == 0) {
          #pragma unroll
          for (int e = 0; e < NE; ++e)
            v += coefS[m_loc * NE + e] * biasS[e * 64 + n_loc];
        }
        if (ELU_ACT) v = v > 0.f ? v : expm1f(v);
        if (FINAL) atomicAdd(&outf[grow * NOUT + bn0 + n_loc], v);
        else       next_x[grow * IN2 + LAT + bn0 + n_loc] = f2bf(v);
      }
    }
  }
}

extern "C" void kernel_launch(void* const* d_in, const int* in_sizes, int n_in,
                              void* d_out, int out_size, void* d_ws, size_t ws_size,
                              hipStream_t stream)
{
  const float* z   = (const float*)d_in[0];
  const float* c   = (const float*)d_in[1];
  const float* w0  = (const float*)d_in[2];
  const float* b0  = (const float*)d_in[3];
  const float* w1  = (const float*)d_in[4];
  const float* b1  = (const float*)d_in[5];
  const float* w2  = (const float*)d_in[6];
  const float* b2  = (const float*)d_in[7];
  const float* gw1 = (const float*)d_in[8];
  const float* gb1 = (const float*)d_in[9];
  const float* gw2 = (const float*)d_in[10];
  const float* gb2 = (const float*)d_in[11];
  const float* gw3 = (const float*)d_in[12];
  const float* gb3 = (const float*)d_in[13];
  float* out = (float*)d_out;

  // workspace layout (bytes), total ~58.9 MB
  char* ws = (char*)d_ws;
  float*          coef = (float*)         (ws + 0);          // 131072
  unsigned short* x1   = (unsigned short*)(ws + 131072);     // 4096*576*2
  unsigned short* x2   = (unsigned short*)(ws + 4849664);    // 4096*1088*2
  unsigned short* x3   = (unsigned short*)(ws + 13762560);
  unsigned short* Wt0  = (unsigned short*)(ws + 22675456);   // 8*1024*576*2
  unsigned short* Wt1  = (unsigned short*)(ws + 32112640);   // 8*1024*1088*2
  unsigned short* Wt2  = (unsigned short*)(ws + 49938432);   // 8*512*1088*2

  hipMemsetAsync(out, 0, (size_t)B_ * FRAME * sizeof(float), stream);
  gate_kernel<<<B_ / 16, 256, 0, stream>>>(z, c, gw1, gb1, gw2, gb2, gw3, gb3, coef);
  build_x<<<(B_ * IN1) / 256, 256, 0, stream>>>(z, c, x1, x2, x3);
  transpose_cast<<<dim3(HID / 32, IN1 / 32, NE), dim3(32, 8), 0, stream>>>(w0, Wt0, IN1, HID);
  transpose_cast<<<dim3(HID / 32, IN2 / 32, NE), dim3(32, 8), 0, stream>>>(w1, Wt1, IN2, HID);
  transpose_cast<<<dim3(FRAME / 32, IN2 / 32, NE), dim3(32, 8), 0, stream>>>(w2, Wt2, IN2, FRAME);

  gemm_moe<IN1, HID, NE, true, false><<<dim3(32, 16), 256, 0, stream>>>(x1, Wt0, b0, coef, x2, nullptr);
  gemm_moe<IN2, HID, NE, true, false><<<dim3(32, 16), 256, 0, stream>>>(x2, Wt1, b1, coef, x3, nullptr);
  gemm_moe<IN2, FRAME, 4, false, true><<<dim3(32, 8, 2), 256, 0, stream>>>(x3, Wt2, b2, coef, nullptr, out);
}

// Round 3
// 420.646 us; speedup vs baseline: 1.7853x; 1.6086x over previous
//
#include <hip/hip_runtime.h>
#include <cstdint>
#include <cstddef>

#define B_    4096
#define LAT   64
#define FRAME 512
#define HID   1024
#define NE    8
#define GH    128
#define IN1   576   // LAT + FRAME
#define IN2   1088  // LAT + HID

typedef __bf16 bf16x8 __attribute__((ext_vector_type(8)));
typedef float  f32x4  __attribute__((ext_vector_type(4)));

// round-to-nearest-even fp32 -> bf16
__device__ inline unsigned short f2bf(float f) {
  union { float f; uint32_t u; } c; c.f = f;
  uint32_t u = c.u;
  return (unsigned short)((u + 0x7FFFu + ((u >> 16) & 1u)) >> 16);
}

// async global->LDS, 16B per lane; LDS dest = wave-uniform base + lane*16
__device__ inline void async16(const void* g, void* l) {
  __builtin_amdgcn_global_load_lds(
      (__attribute__((address_space(1))) void*)(void*)g,
      (__attribute__((address_space(3))) void*)l, 16, 0, 0);
}

// ---------------- gate MLP -> coef [B, 8] fp32 ----------------
__global__ __launch_bounds__(256) void gate_kernel(
    const float* __restrict__ z, const float* __restrict__ c,
    const float* __restrict__ gw1, const float* __restrict__ gb1,
    const float* __restrict__ gw2, const float* __restrict__ gb2,
    const float* __restrict__ gw3, const float* __restrict__ gb3,
    float* __restrict__ coef)
{
  __shared__ float xs[16][IN1 + 1];
  __shared__ float hs[16][GH + 1];
  __shared__ float h2s[16][GH + 1];
  __shared__ float ls[16][NE];
  const int tid = threadIdx.x;
  const int r0 = blockIdx.x * 16;

  for (int i = tid; i < 16 * IN1; i += 256) {
    int r = i / IN1, j = i - r * IN1;
    xs[r][j] = (j < LAT) ? z[(size_t)(r0 + r) * LAT + j]
                         : c[(size_t)(r0 + r) * FRAME + (j - LAT)];
  }
  __syncthreads();
  {
    const int col = tid & 127, rbase = tid >> 7;
    float acc[8];
    for (int q = 0; q < 8; ++q) acc[q] = gb1[col];
    for (int i = 0; i < IN1; ++i) {
      float w = gw1[(size_t)i * GH + col];
      for (int q = 0; q < 8; ++q) acc[q] += w * xs[rbase + 2 * q][i];
    }
    for (int q = 0; q < 8; ++q) {
      float v = acc[q];
      hs[rbase + 2 * q][col] = v > 0.f ? v : expm1f(v);
    }
  }
  __syncthreads();
  {
    const int col = tid & 127, rbase = tid >> 7;
    float acc[8];
    for (int q = 0; q < 8; ++q) acc[q] = gb2[col];
    for (int i = 0; i < GH; ++i) {
      float w = gw2[(size_t)i * GH + col];
      for (int q = 0; q < 8; ++q) acc[q] += w * hs[rbase + 2 * q][i];
    }
    for (int q = 0; q < 8; ++q) {
      float v = acc[q];
      h2s[rbase + 2 * q][col] = v > 0.f ? v : expm1f(v);
    }
  }
  __syncthreads();
  if (tid < 128) {
    int r = tid >> 3, e = tid & 7;
    float acc = gb3[e];
    for (int i = 0; i < GH; ++i) acc += h2s[r][i] * gw3[(size_t)i * NE + e];
    ls[r][e] = acc;
  }
  __syncthreads();
  if (tid < 16) {
    int r = tid;
    float m = ls[r][0];
    for (int e = 1; e < NE; ++e) m = fmaxf(m, ls[r][e]);
    float ex[NE], s = 0.f;
    for (int e = 0; e < NE; ++e) { ex[e] = expf(ls[r][e] - m); s += ex[e]; }
    float inv = 1.f / s;
    for (int e = 0; e < NE; ++e) coef[(size_t)(r0 + r) * NE + e] = ex[e] * inv;
  }
}

// ================= NEW PATH: X'-expanded single-acc GEMMs =================

// weights [E][K][N] fp32 -> Wt [N][E*K] bf16 (B^T layout, e-major k')
__global__ __launch_bounds__(256) void transpose_cast_flat(
    const float* __restrict__ in, unsigned short* __restrict__ out, int K, int N)
{
  __shared__ float t[32][33];
  const int e = blockIdx.z;
  const int n0 = blockIdx.x * 32, k0 = blockIdx.y * 32;
  const float* ine = in + (size_t)e * K * N;
  const int tx = threadIdx.x, ty = threadIdx.y;
  for (int it = 0; it < 4; ++it)
    t[ty + it * 8][tx] = ine[(size_t)(k0 + ty + it * 8) * N + n0 + tx];
  __syncthreads();
  for (int it = 0; it < 4; ++it)
    out[(size_t)(n0 + ty + it * 8) * (NE * K) + (size_t)e * K + k0 + tx] =
        f2bf(t[tx][ty + it * 8]);
}

// X'1[b, e*IN1 + j] = bf16(coef[b,e] * x0[b,j]),  x0 = [z | c]
__global__ __launch_bounds__(256) void build_xp1(
    const float* __restrict__ z, const float* __restrict__ c,
    const float* __restrict__ coef, unsigned short* __restrict__ xp)
{
  int idx = blockIdx.x * 256 + threadIdx.x;   // B_*IN1 exact
  int b = idx / IN1, j = idx - b * IN1;
  float v = (j < LAT) ? z[(size_t)b * LAT + j] : c[(size_t)b * FRAME + (j - LAT)];
  const float* cf = coef + (size_t)b * NE;
  unsigned short* row = xp + (size_t)b * (NE * IN1) + j;
  #pragma unroll
  for (int e = 0; e < NE; ++e) row[(size_t)e * IN1] = f2bf(cf[e] * v);
}

// GEMM: part[z][b][n] = sum_{k in chunk z} X'[b,k'] * Wt[n,k']
// 128x128 tile, 4 waves of 4x4 16x16x32 MFMAs, single fp32 accumulator.
template<int KP, int NOUT, int KSTEPS>
__global__ __launch_bounds__(256, 3) void gemm_bt(
    const unsigned short* __restrict__ Xp,   // [B_][KP]
    const unsigned short* __restrict__ Wt,   // [NOUT][KP]
    float* __restrict__ part)                // [KSPLIT][B_][NOUT]
{
  __shared__ __align__(16) unsigned short As[128 * 64];
  __shared__ __align__(16) unsigned short Bs[128 * 64];
  const int tid = threadIdx.x;
  const int wave = tid >> 6, lane = tid & 63;
  const int wm = wave & 1, wn = wave >> 1;
  const int quad = lane >> 4, l16 = lane & 15;
  const int bm0 = blockIdx.x * 128, bn0 = blockIdx.y * 128;
  const int kbase = blockIdx.z * (KSTEPS * 64);

  f32x4 acc[4][4];
  #pragma unroll
  for (int mi = 0; mi < 4; ++mi)
    #pragma unroll
    for (int ni = 0; ni < 4; ++ni)
      #pragma unroll
      for (int r = 0; r < 4; ++r) acc[mi][ni][r] = 0.f;

  const int srow  = wave * 8 + (lane >> 3);                  // + it*32
  const int skoff = (((lane & 7) ^ ((lane >> 3) & 7)) * 8);  // swizzled src granule

  for (int ki = 0; ki < KSTEPS; ++ki) {
    const int k0 = kbase + ki * 64;
    #pragma unroll
    for (int it = 0; it < 4; ++it) {
      async16(Xp + (size_t)(bm0 + it * 32 + srow) * KP + k0 + skoff,
              &As[it * 2048 + wave * 512]);
      async16(Wt + (size_t)(bn0 + it * 32 + srow) * KP + k0 + skoff,
              &Bs[it * 2048 + wave * 512]);
    }
    __syncthreads();
    #pragma unroll
    for (int ks = 0; ks < 64; ks += 32) {
      bf16x8 af[4], bv[4];
      #pragma unroll
      for (int mi = 0; mi < 4; ++mi) {
        const int r = wm * 64 + mi * 16 + l16;
        const int g = (ks / 8 + quad) ^ (r & 7);
        af[mi] = *(const bf16x8*)&As[r * 64 + g * 8];
      }
      #pragma unroll
      for (int ni = 0; ni < 4; ++ni) {
        const int r = wn * 64 + ni * 16 + l16;
        const int g = (ks / 8 + quad) ^ (r & 7);
        bv[ni] = *(const bf16x8*)&Bs[r * 64 + g * 8];
      }
      #pragma unroll
      for (int mi = 0; mi < 4; ++mi)
        #pragma unroll
        for (int ni = 0; ni < 4; ++ni)
          acc[mi][ni] = __builtin_amdgcn_mfma_f32_16x16x32_bf16(
              af[mi], bv[ni], acc[mi][ni], 0, 0, 0);
    }
    __syncthreads();
  }

  float* po = part + (size_t)blockIdx.z * B_ * NOUT;
  #pragma unroll
  for (int mi = 0; mi < 4; ++mi)
    #pragma unroll
    for (int r = 0; r < 4; ++r) {
      const int m_loc = wm * 64 + mi * 16 + quad * 4 + r;
      #pragma unroll
      for (int ni = 0; ni < 4; ++ni) {
        const int n_loc = wn * 64 + ni * 16 + l16;
        po[(size_t)(bm0 + m_loc) * NOUT + bn0 + n_loc] = acc[mi][ni][r];
      }
    }
}

// epilogue+expand: act = ELU(sum_s part[s] + coef@bias); X'[b,e*IN2+j] = bf16(coef*val)
// j<64 -> z columns.
template<int KSPLIT>
__global__ __launch_bounds__(256) void expand_xp(
    const float* __restrict__ part,   // [KSPLIT][B_][HID]
    const float* __restrict__ bias,   // [NE][HID]
    const float* __restrict__ z,
    const float* __restrict__ coef,
    unsigned short* __restrict__ xp)  // [B_][NE*IN2]
{
  int idx = blockIdx.x * 256 + threadIdx.x;   // B_*IN2 exact
  int b = idx / IN2, j = idx - b * IN2;
  const float* cf = coef + (size_t)b * NE;
  float cl[NE];
  #pragma unroll
  for (int e = 0; e < NE; ++e) cl[e] = cf[e];
  float v;
  if (j < LAT) {
    v = z[(size_t)b * LAT + j];
  } else {
    int h = j - LAT;
    v = 0.f;
    #pragma unroll
    for (int s = 0; s < KSPLIT; ++s)
      v += part[(size_t)s * B_ * HID + (size_t)b * HID + h];
    #pragma unroll
    for (int e = 0; e < NE; ++e) v += cl[e] * bias[(size_t)e * HID + h];
    v = v > 0.f ? v : expm1f(v);
  }
  unsigned short* row = xp + (size_t)b * (NE * IN2) + j;
  #pragma unroll
  for (int e = 0; e < NE; ++e) row[(size_t)e * IN2] = f2bf(cl[e] * v);
}

// final: out[b,n] = sum_s part[s][b][n] + sum_e coef[b,e]*bias2[e,n]
template<int KSPLIT>
__global__ __launch_bounds__(256) void final_out(
    const float* __restrict__ part,   // [KSPLIT][B_][FRAME]
    const float* __restrict__ bias2,  // [NE][FRAME]
    const float* __restrict__ coef,
    float* __restrict__ out)
{
  int idx = blockIdx.x * 256 + threadIdx.x;   // B_*FRAME exact
  int b = idx / FRAME, n = idx - b * FRAME;
  float v = 0.f;
  #pragma unroll
  for (int s = 0; s < KSPLIT; ++s)
    v += part[(size_t)s * B_ * FRAME + idx];
  const float* cf = coef + (size_t)b * NE;
  #pragma unroll
  for (int e = 0; e < NE; ++e) v += cf[e] * bias2[(size_t)e * FRAME + n];
  out[idx] = v;
}

// ================= FALLBACK PATH (round-2, fits in 59 MB) =================

__global__ __launch_bounds__(256) void build_x(
    const float* __restrict__ z, const float* __restrict__ c,
    unsigned short* __restrict__ x1, unsigned short* __restrict__ x2,
    unsigned short* __restrict__ x3)
{
  int idx = blockIdx.x * 256 + threadIdx.x;
  if (idx >= B_ * IN1) return;
  int b = idx / IN1, j = idx - b * IN1;
  float v = (j < LAT) ? z[(size_t)b * LAT + j] : c[(size_t)b * FRAME + (j - LAT)];
  unsigned short h = f2bf(v);
  x1[(size_t)b * IN1 + j] = h;
  if (j < LAT) {
    x2[(size_t)b * IN2 + j] = h;
    x3[(size_t)b * IN2 + j] = h;
  }
}

__global__ __launch_bounds__(256) void transpose_cast(
    const float* __restrict__ in, unsigned short* __restrict__ out, int K, int N)
{
  __shared__ float t[32][33];
  const int e = blockIdx.z;
  const int n0 = blockIdx.x * 32, k0 = blockIdx.y * 32;
  const float* ine = in + (size_t)e * K * N;
  unsigned short* oute = out + (size_t)e * N * K;
  const int tx = threadIdx.x, ty = threadIdx.y;
  for (int it = 0; it < 4; ++it)
    t[ty + it * 8][tx] = ine[(size_t)(k0 + ty + it * 8) * N + n0 + tx];
  __syncthreads();
  for (int it = 0; it < 4; ++it)
    oute[(size_t)(n0 + ty + it * 8) * K + k0 + tx] = f2bf(t[tx][ty + it * 8]);
}

template<int KDIM, int NOUT, int ECNT, bool ELU_ACT, bool FINAL>
__global__ __launch_bounds__(256) void gemm_moe(
    const unsigned short* __restrict__ X,
    const unsigned short* __restrict__ Wt,
    const float* __restrict__ bias,
    const float* __restrict__ coef,
    unsigned short* __restrict__ next_x,
    float* __restrict__ outf)
{
  __shared__ __align__(16) unsigned short As[128 * 64];
  __shared__ __align__(16) unsigned short Bs[64 * 64];
  __shared__ float coefS[128 * NE];
  __shared__ float biasS[NE * 64];

  const int tid = threadIdx.x;
  const int wave = tid >> 6, lane = tid & 63;
  const int wm = wave & 1, wn = wave >> 1;
  const int quad = lane >> 4, l16 = lane & 15;
  const int bm0 = blockIdx.x * 128, bn0 = blockIdx.y * 64;
  const int ebase = FINAL ? blockIdx.z * ECNT : 0;

  for (int i = tid; i < 128 * NE; i += 256)
    coefS[i] = coef[(size_t)(bm0 + (i >> 3)) * NE + (i & 7)];
  for (int i = tid; i < NE * 64; i += 256)
    biasS[i] = bias[(size_t)(i >> 6) * NOUT + bn0 + (i & 63)];

  f32x4 accT[4][2];
  #pragma unroll
  for (int mi = 0; mi < 4; ++mi)
    #pragma unroll
    for (int ni = 0; ni < 2; ++ni)
      #pragma unroll
      for (int r = 0; r < 4; ++r) accT[mi][ni][r] = 0.f;

  const int srow  = wave * 8 + (lane >> 3);
  const int skoff = (((lane & 7) ^ ((lane >> 3) & 7)) * 8);

  for (int e = 0; e < ECNT; ++e) {
    const size_t eoff = (size_t)(ebase + e) * NOUT * KDIM;
    f32x4 accE[4][2];
    #pragma unroll
    for (int mi = 0; mi < 4; ++mi)
      #pragma unroll
      for (int ni = 0; ni < 2; ++ni)
        #pragma unroll
        for (int r = 0; r < 4; ++r) accE[mi][ni][r] = 0.f;

    for (int k0 = 0; k0 < KDIM; k0 += 64) {
      #pragma unroll
      for (int it = 0; it < 4; ++it)
        async16(X + (size_t)(bm0 + it * 32 + srow) * KDIM + k0 + skoff,
                &As[it * 2048 + wave * 512]);
      #pragma unroll
      for (int it = 0; it < 2; ++it)
        async16(Wt + eoff + (size_t)(bn0 + it * 32 + srow) * KDIM + k0 + skoff,
                &Bs[it * 2048 + wave * 512]);
      __syncthreads();
      #pragma unroll
      for (int ks = 0; ks < 64; ks += 32) {
        bf16x8 af[4], bv[2];
        #pragma unroll
        for (int mi = 0; mi < 4; ++mi) {
          const int r = wm * 64 + mi * 16 + l16;
          const int g = (ks / 8 + quad) ^ (r & 7);
          af[mi] = *(const bf16x8*)&As[r * 64 + g * 8];
        }
        #pragma unroll
        for (int ni = 0; ni < 2; ++ni) {
          const int r = wn * 32 + ni * 16 + l16;
          const int g = (ks / 8 + quad) ^ (r & 7);
          bv[ni] = *(const bf16x8*)&Bs[r * 64 + g * 8];
        }
        #pragma unroll
        for (int mi = 0; mi < 4; ++mi)
          #pragma unroll
          for (int ni = 0; ni < 2; ++ni)
            accE[mi][ni] = __builtin_amdgcn_mfma_f32_16x16x32_bf16(
                af[mi], bv[ni], accE[mi][ni], 0, 0, 0);
      }
      __syncthreads();
    }
    #pragma unroll
    for (int mi = 0; mi < 4; ++mi) {
      float cf[4];
      #pragma unroll
      for (int r = 0; r < 4; ++r)
        cf[r] = coefS[(wm * 64 + mi * 16 + quad * 4 + r) * NE + ebase + e];
      #pragma unroll
      for (int ni = 0; ni < 2; ++ni)
        #pragma unroll
        for (int r = 0; r < 4; ++r)
          accT[mi][ni][r] += cf[r] * accE[mi][ni][r];
    }
  }

  #pragma unroll
  for (int mi = 0; mi < 4; ++mi) {
    #pragma unroll
    for (int r = 0; r < 4; ++r) {
      const int m_loc = wm * 64 + mi * 16 + quad * 4 + r;
      const size_t grow = (size_t)(bm0 + m_loc);
      #pragma unroll
      for (int ni = 0; ni < 2; ++ni) {
        const int n_loc = wn * 32 + ni * 16 + l16;
        float v = accT[mi][ni][r];
        if (!FINAL || blockIdx.z == 0) {
          #pragma unroll
          for (int e = 0; e < NE; ++e)
            v += coefS[m_loc * NE + e] * biasS[e * 64 + n_loc];
        }
        if (ELU_ACT) v = v > 0.f ? v : expm1f(v);
        if (FINAL) atomicAdd(&outf[grow * NOUT + bn0 + n_loc], v);
        else       next_x[grow * IN2 + LAT + bn0 + n_loc] = f2bf(v);
      }
    }
  }
}

// ============================ launch ============================

extern "C" void kernel_launch(void* const* d_in, const int* in_sizes, int n_in,
                              void* d_out, int out_size, void* d_ws, size_t ws_size,
                              hipStream_t stream)
{
  const float* z   = (const float*)d_in[0];
  const float* c   = (const float*)d_in[1];
  const float* w0  = (const float*)d_in[2];
  const float* b0  = (const float*)d_in[3];
  const float* w1  = (const float*)d_in[4];
  const float* b1  = (const float*)d_in[5];
  const float* w2  = (const float*)d_in[6];
  const float* b2  = (const float*)d_in[7];
  const float* gw1 = (const float*)d_in[8];
  const float* gb1 = (const float*)d_in[9];
  const float* gw2 = (const float*)d_in[10];
  const float* gb2 = (const float*)d_in[11];
  const float* gw3 = (const float*)d_in[12];
  const float* gb3 = (const float*)d_in[13];
  float* out = (float*)d_out;
  char* ws = (char*)d_ws;

  // ---- new path workspace (aliased): 122,814,464 bytes ----
  const size_t OFF_XP   = 131072;                    // X' region, 71,303,168 (reused x3)
  const size_t OFF_WT   = 71434240;                  // Wt region, 17,825,792 (reused x3)
  const size_t OFF_PART = 89260032;                  // partials, 33,554,432 (reused x3)
  const size_t NEED     = 122814464;

  float* coef = (float*)(ws + 0);

  if (ws_size >= NEED) {
    unsigned short* Xp   = (unsigned short*)(ws + OFF_XP);
    unsigned short* Wt   = (unsigned short*)(ws + OFF_WT);
    float*          part = (float*)         (ws + OFF_PART);

    gate_kernel<<<B_ / 16, 256, 0, stream>>>(z, c, gw1, gb1, gw2, gb2, gw3, gb3, coef);
    build_xp1<<<(B_ * IN1) / 256, 256, 0, stream>>>(z, c, coef, Xp);

    // layer 1: K' = 8*576 = 4608, N = 1024, split 2 (36 k-steps each)
    transpose_cast_flat<<<dim3(HID / 32, IN1 / 32, NE), dim3(32, 8), 0, stream>>>(w0, Wt, IN1, HID);
    gemm_bt<NE * IN1, HID, 36><<<dim3(32, 8, 2), 256, 0, stream>>>(Xp, Wt, part);
    expand_xp<2><<<(B_ * IN2) / 256, 256, 0, stream>>>(part, b0, z, coef, Xp);

    // layer 2: K' = 8*1088 = 8704, N = 1024, split 2 (68 k-steps each)
    transpose_cast_flat<<<dim3(HID / 32, IN2 / 32, NE), dim3(32, 8), 0, stream>>>(w1, Wt, IN2, HID);
    gemm_bt<NE * IN2, HID, 68><<<dim3(32, 8, 2), 256, 0, stream>>>(Xp, Wt, part);
    expand_xp<2><<<(B_ * IN2) / 256, 256, 0, stream>>>(part, b1, z, coef, Xp);

    // layer 3: K' = 8704, N = 512, split 4 (34 k-steps each)
    transpose_cast_flat<<<dim3(FRAME / 32, IN2 / 32, NE), dim3(32, 8), 0, stream>>>(w2, Wt, IN2, FRAME);
    gemm_bt<NE * IN2, FRAME, 34><<<dim3(32, 4, 4), 256, 0, stream>>>(Xp, Wt, part);
    final_out<4><<<(B_ * FRAME) / 256, 256, 0, stream>>>(part, b2, coef, out);
    return;
  }

  // ---- fallback: round-2 pipeline (58,851,328 bytes) ----
  unsigned short* x1  = (unsigned short*)(ws + 131072);
  unsigned short* x2  = (unsigned short*)(ws + 4849664);
  unsigned short* x3  = (unsigned short*)(ws + 13762560);
  unsigned short* Wt0 = (unsigned short*)(ws + 22675456);
  unsigned short* Wt1 = (unsigned short*)(ws + 32112640);
  unsigned short* Wt2 = (unsigned short*)(ws + 49938432);

  hipMemsetAsync(out, 0, (size_t)B_ * FRAME * sizeof(float), stream);
  gate_kernel<<<B_ / 16, 256, 0, stream>>>(z, c, gw1, gb1, gw2, gb2, gw3, gb3, coef);
  build_x<<<(B_ * IN1) / 256, 256, 0, stream>>>(z, c, x1, x2, x3);
  transpose_cast<<<dim3(HID / 32, IN1 / 32, NE), dim3(32, 8), 0, stream>>>(w0, Wt0, IN1, HID);
  transpose_cast<<<dim3(HID / 32, IN2 / 32, NE), dim3(32, 8), 0, stream>>>(w1, Wt1, IN2, HID);
  transpose_cast<<<dim3(FRAME / 32, IN2 / 32, NE), dim3(32, 8), 0, stream>>>(w2, Wt2, IN2, FRAME);
  gemm_moe<IN1, HID, NE, true, false><<<dim3(32, 16), 256, 0, stream>>>(x1, Wt0, b0, coef, x2, nullptr);
  gemm_moe<IN2, HID, NE, true, false><<<dim3(32, 16), 256, 0, stream>>>(x2, Wt1, b1, coef, x3, nullptr);
  gemm_moe<IN2, FRAME, 4, false, true><<<dim3(32, 8, 2), 256, 0, stream>>>(x3, Wt2, b2, coef, nullptr, out);
}